// Round 1
// 782.573 us; speedup vs baseline: 1.0010x; 1.0010x over previous
//
#include <hip/hip_runtime.h>
#include <cstdint>

// ---------------------------------------------------------------------------
// GatedCrossAttention  (E=1024, Z=256, L=2048, B=8)
// Main GEMMs: 256x256 tile, BK=64, 8 waves, 4-phase/K-tile schedule with
// counted vmcnt (T1+T2+T3+T4+T5).  k-GEMM (N=256) stays on the 128^2 engine.
// ---------------------------------------------------------------------------

#define EN 1024
#define ZN 256
#define LN_ 2048
#define BN_ 8
#define MROWS (LN_ * BN_)          // 16384
#define QRU_N (2 * EN + ZN)        // 2304
#define LEN_SCALE 0.022097086912079608f  // 1/sqrt(2048)

typedef unsigned short u16;
typedef __bf16 bf16x8 __attribute__((ext_vector_type(8)));
typedef float f32x4 __attribute__((ext_vector_type(4)));

// ---- bf16 helpers ---------------------------------------------------------
__device__ __forceinline__ u16 f2bf(float f) {
    unsigned int u = __float_as_uint(f);
    u = (u + 0x7fff + ((u >> 16) & 1)) >> 16;
    return (u16)u;
}
__device__ __forceinline__ float bf2f(u16 s) {
    return __uint_as_float(((unsigned int)s) << 16);
}
__device__ __forceinline__ void store_bf16x4(u16* p, float a, float b, float c, float d) {
    union { u16 h[4]; uint2 v; } pk;
    pk.h[0] = f2bf(a); pk.h[1] = f2bf(b); pk.h[2] = f2bf(c); pk.h[3] = f2bf(d);
    *(uint2*)p = pk.v;
}

// ---- async global->LDS (16B/lane, wave-uniform LDS base + lane*16) --------
__device__ __forceinline__ void async_load16(const void* g, void* l) {
    __builtin_amdgcn_global_load_lds(
        (const __attribute__((address_space(1))) void*)g,
        (__attribute__((address_space(3))) void*)l,
        16, 0, 0);
}

#define GB_BAR()  asm volatile("s_barrier" ::: "memory")
#define GB_VMC(n) asm volatile("s_waitcnt vmcnt(" #n ")" ::: "memory")

// ===========================================================================
// 256x256 engine.  LDS tile rows are 64 elems (=2 k-steps of 32); 16B chunk c
// of row r is stored at chunk c^(r&7) (swizzle applied on the GLOBAL source
// col of global_load_lds, undone on ds_read; bank-conflict-free, measured 0).
// Per wave: 128x64 output = acc[8][4] f32x4.  Phases per K-tile:
//   p0 (M0,N0): read A-h0(8) B-h0(4); stage A-h0' ; tail vmcnt(4)
//   p1 (M0,N1): read B-h1(4)        ; stage B-h0' ; tail vmcnt(4)
//   p2 (M1,N1): read A-h1(8)        ; stage B-h1' ; no wait
//   p3 (M1,N0): read B-h0(4)        ; stage A-h1' ; tail vmcnt(4)
// Halves are consumption-defined: A-half h = rows with bit6==h
// ({0-63,128-191} / {64-127,192-255}), B-half h = rows with bit5==h.
// FIFO vmcnt accounting (verified): steady state 6 loads outstanding at each
// tail wait; vmcnt(4) retires exactly the half-tile the next phase reads.
// Last K-tile peeled (no staging; vmcnt(2)/vmcnt(0) drains).
// ===========================================================================
template <int MH>
__device__ __forceinline__ void rd_a(const u16* __restrict__ s, int wm, int l16, int quad,
                                     bf16x8 (&af)[4][2]) {
#pragma unroll
    for (int mi = 0; mi < 4; ++mi)
#pragma unroll
        for (int ks = 0; ks < 2; ++ks)
            af[mi][ks] = *(const bf16x8*)&s[(wm * 128 + MH * 64 + mi * 16 + l16) * 64 +
                                            ((ks * 4 + quad) ^ (l16 & 7)) * 8];
}
template <int NH>
__device__ __forceinline__ void rd_b(const u16* __restrict__ s, int wn, int l16, int quad,
                                     bf16x8 (&bv)[2][2]) {
#pragma unroll
    for (int ni = 0; ni < 2; ++ni)
#pragma unroll
        for (int ks = 0; ks < 2; ++ks)
            bv[ni][ks] = *(const bf16x8*)&s[(wn * 64 + NH * 32 + ni * 16 + l16) * 64 +
                                            ((ks * 4 + quad) ^ (l16 & 7)) * 8];
}
template <int MH, int NH>
__device__ __forceinline__ void quad_mfma(const bf16x8 (&af)[4][2], const bf16x8 (&bv)[2][2],
                                          f32x4 (&acc)[8][4]) {
    __builtin_amdgcn_s_setprio(1);
#pragma unroll
    for (int mi = 0; mi < 4; ++mi)
#pragma unroll
        for (int ni = 0; ni < 2; ++ni)
#pragma unroll
            for (int ks = 0; ks < 2; ++ks)
                acc[MH * 4 + mi][NH * 2 + ni] = __builtin_amdgcn_mfma_f32_16x16x32_bf16(
                    af[mi][ks], bv[ni][ks], acc[MH * 4 + mi][NH * 2 + ni], 0, 0, 0);
    __builtin_amdgcn_s_setprio(0);
}

template <typename Epi>
__global__ __launch_bounds__(512, 2)
void gemm256(const u16* __restrict__ A, const u16* __restrict__ B,
             long long batchStrideA, long long batchStrideB, int K, Epi epi)
{
    __shared__ __align__(16) u16 As[2][256 * 64];
    __shared__ __align__(16) u16 Bs[2][256 * 64];

    const int tid  = threadIdx.x;
    const int lane = tid & 63;
    const int w    = tid >> 6;            // 0..7
    const int wm   = w >> 2, wn = w & 3;  // 2x4 wave grid
    const int quad = lane >> 4, l16 = lane & 15;
    const int bz   = blockIdx.z;

    // XCD-aware swizzle (bijective: all our grids have nwg % 8 == 0)
    const int gx = gridDim.x;
    const int nwg = gx * gridDim.y;
    const int orig = blockIdx.y * gx + blockIdx.x;
    const int swz = ((nwg & 7) == 0) ? ((orig & 7) * (nwg >> 3) + (orig >> 3)) : orig;
    const long long m0 = (long long)(swz / gx) * 256;
    const long long n0 = (long long)(swz % gx) * 256;

    const u16* Ab = A + bz * batchStrideA;
    const u16* Bb = B + bz * batchStrideB;

    // staging geometry: each wave-instr covers 8 rows; lane l -> row +l/8,
    // dest chunk l&7; swizzled source col chunk = (l&7)^(l>>3)
    const int srow = lane >> 3;
    const int scol = ((lane & 7) ^ srow) * 8;

    int rAb[2][2], rBb[2][2];
#pragma unroll
    for (int h = 0; h < 2; ++h)
#pragma unroll
        for (int j = 0; j < 2; ++j) {
            const int gg = w * 2 + j;     // 0..15 (wave-uniform)
            rAb[h][j] = (gg < 8) ? (h * 64 + gg * 8) : (128 + h * 64 + (gg - 8) * 8);
            rBb[h][j] = (gg >> 2) * 64 + h * 32 + (gg & 3) * 8;
        }
    const u16* pA[2][2]; const u16* pB[2][2];
#pragma unroll
    for (int h = 0; h < 2; ++h)
#pragma unroll
        for (int j = 0; j < 2; ++j) {
            pA[h][j] = Ab + (m0 + rAb[h][j] + srow) * K + scol;
            pB[h][j] = Bb + (n0 + rBb[h][j] + srow) * K + scol;
        }

    const f32x4 fz = {0.f, 0.f, 0.f, 0.f};
    f32x4 acc[8][4];
#pragma unroll
    for (int i = 0; i < 8; ++i)
#pragma unroll
        for (int j = 0; j < 4; ++j) acc[i][j] = fz;

    bf16x8 af[4][2], bv[2][2];
    const int NT = K >> 6;

    // ---- prologue: stage tile 0 into buf 0, order Ah0,Bh0,Bh1,Ah1 ----
    async_load16(pA[0][0], &As[0][rAb[0][0] * 64]);
    async_load16(pA[0][1], &As[0][rAb[0][1] * 64]);
    async_load16(pB[0][0], &Bs[0][rBb[0][0] * 64]);
    async_load16(pB[0][1], &Bs[0][rBb[0][1] * 64]);
    async_load16(pB[1][0], &Bs[0][rBb[1][0] * 64]);
    async_load16(pB[1][1], &Bs[0][rBb[1][1] * 64]);
    async_load16(pA[1][0], &As[0][rAb[1][0] * 64]);
    async_load16(pA[1][1], &As[0][rAb[1][1] * 64]);
    if (NT > 1) {
#pragma unroll
        for (int h = 0; h < 2; ++h)
#pragma unroll
            for (int j = 0; j < 2; ++j) { pA[h][j] += 64; pB[h][j] += 64; }
    }
    GB_VMC(4);   // Ah0,Bh0 of tile 0 landed
    GB_BAR();

    // ---- main loop: compute tile t (buf t&1), stage tile t+1 (buf ^1) ----
    for (int t = 0; t < NT - 1; ++t) {
        const u16* Asc = As[t & 1];
        const u16* Bsc = Bs[t & 1];
        u16* Asn = As[(t & 1) ^ 1];
        u16* Bsn = Bs[(t & 1) ^ 1];

        // p0: (M0,N0)
        rd_a<0>(Asc, wm, l16, quad, af);
        rd_b<0>(Bsc, wn, l16, quad, bv);
        async_load16(pA[0][0], &Asn[rAb[0][0] * 64]);
        async_load16(pA[0][1], &Asn[rAb[0][1] * 64]);
        GB_BAR();
        quad_mfma<0, 0>(af, bv, acc);
        GB_VMC(4);                         // retires B-h1 of tile t
        GB_BAR();
        // p1: (M0,N1)
        rd_b<1>(Bsc, wn, l16, quad, bv);
        async_load16(pB[0][0], &Bsn[rBb[0][0] * 64]);
        async_load16(pB[0][1], &Bsn[rBb[0][1] * 64]);
        GB_BAR();
        quad_mfma<0, 1>(af, bv, acc);
        GB_VMC(4);                         // retires A-h1 of tile t
        GB_BAR();
        // p2: (M1,N1)
        rd_a<1>(Asc, wm, l16, quad, af);
        async_load16(pB[1][0], &Bsn[rBb[1][0] * 64]);
        async_load16(pB[1][1], &Bsn[rBb[1][1] * 64]);
        GB_BAR();
        quad_mfma<1, 1>(af, bv, acc);
        GB_BAR();
        // p3: (M1,N0)
        rd_b<0>(Bsc, wn, l16, quad, bv);
        async_load16(pA[1][0], &Asn[rAb[1][0] * 64]);
        async_load16(pA[1][1], &Asn[rAb[1][1] * 64]);
        GB_BAR();
        quad_mfma<1, 0>(af, bv, acc);
        GB_VMC(4);                         // retires A-h0',B-h0' of tile t+1
        GB_BAR();

        if (t + 2 < NT) {
#pragma unroll
            for (int h = 0; h < 2; ++h)
#pragma unroll
                for (int j = 0; j < 2; ++j) { pA[h][j] += 64; pB[h][j] += 64; }
        }
    }

    // ---- peeled last tile (no staging) ----
    {
        const u16* Asc = As[(NT - 1) & 1];
        const u16* Bsc = Bs[(NT - 1) & 1];
        rd_a<0>(Asc, wm, l16, quad, af);
        rd_b<0>(Bsc, wn, l16, quad, bv);
        GB_BAR();
        quad_mfma<0, 0>(af, bv, acc);
        GB_VMC(2);                         // B-h1 of last tile landed
        GB_BAR();
        rd_b<1>(Bsc, wn, l16, quad, bv);
        GB_BAR();
        quad_mfma<0, 1>(af, bv, acc);
        GB_VMC(0);                         // A-h1 of last tile landed
        GB_BAR();
        rd_a<1>(Asc, wm, l16, quad, af);
        GB_BAR();
        quad_mfma<1, 1>(af, bv, acc);
        GB_BAR();
        rd_b<0>(Bsc, wn, l16, quad, bv);
        GB_BAR();
        quad_mfma<1, 0>(af, bv, acc);
        GB_BAR();
    }

    // epilogue: D[row][col], col = lane&15, row = quad*4 + reg  [m89/m91]
#pragma unroll
    for (int mi = 0; mi < 8; ++mi)
#pragma unroll
        for (int ni = 0; ni < 4; ++ni)
#pragma unroll
            for (int r = 0; r < 4; ++r) {
                int m = (int)m0 + wm * 128 + mi * 16 + quad * 4 + r;
                int n = (int)n0 + wn * 64 + ni * 16 + l16;
                epi(bz, m, n, acc[mi][ni][r]);
            }
}

// ===========================================================================
// 128x128 engine (kept for the k-GEMM, N=256 -> needs small tiles for grid)
// ===========================================================================
template <typename Epi>
__global__ __launch_bounds__(256)
void gemm_bt(const u16* __restrict__ A, const u16* __restrict__ B,
             long long batchStrideA, long long batchStrideB, int K, Epi epi)
{
    __shared__ __align__(16) u16 As[128 * 64];
    __shared__ __align__(16) u16 Bs[128 * 64];

    const int tid  = threadIdx.x;
    const int lane = tid & 63;
    const int w    = tid >> 6;
    const int wm   = w >> 1, wn = w & 1;
    const int bz   = blockIdx.z;
    const long long m0 = (long long)blockIdx.y * 128;
    const long long n0 = (long long)blockIdx.x * 128;
    const u16* Ab = A + bz * batchStrideA;
    const u16* Bb = B + bz * batchStrideB;

    const int srow = lane >> 3;
    const int scol = ((lane & 7) ^ srow) * 8;
    const int quad = lane >> 4;
    const int l16  = lane & 15;

    const int choff0 = ((quad     ^ (l16 & 7)) * 8);
    const int choff1 = (((4 + quad) ^ (l16 & 7)) * 8);

    const f32x4 fzero = {0.f, 0.f, 0.f, 0.f};
    f32x4 acc[4][4];
#pragma unroll
    for (int i = 0; i < 4; ++i)
#pragma unroll
        for (int j = 0; j < 4; ++j) acc[i][j] = fzero;

    for (int k0 = 0; k0 < K; k0 += 64) {
        __syncthreads();
#pragma unroll
        for (int t = 0; t < 4; ++t) {
            const int rbase = w * 32 + t * 8;
            async_load16(Ab + (m0 + rbase + srow) * K + (k0 + scol), (void*)&As[rbase * 64]);
            async_load16(Bb + (n0 + rbase + srow) * K + (k0 + scol), (void*)&Bs[rbase * 64]);
        }
        __builtin_amdgcn_s_waitcnt(0);
        __syncthreads();

#pragma unroll
        for (int h = 0; h < 2; ++h) {
            const int ch = h ? choff1 : choff0;
            bf16x8 af[4], bfv[4];
#pragma unroll
            for (int mi = 0; mi < 4; ++mi)
                af[mi] = *(const bf16x8*)&As[(wm * 64 + mi * 16 + l16) * 64 + ch];
#pragma unroll
            for (int ni = 0; ni < 4; ++ni)
                bfv[ni] = *(const bf16x8*)&Bs[(wn * 64 + ni * 16 + l16) * 64 + ch];
#pragma unroll
            for (int mi = 0; mi < 4; ++mi)
#pragma unroll
                for (int ni = 0; ni < 4; ++ni)
                    acc[mi][ni] = __builtin_amdgcn_mfma_f32_16x16x32_bf16(
                        af[mi], bfv[ni], acc[mi][ni], 0, 0, 0);
        }
    }

#pragma unroll
    for (int mi = 0; mi < 4; ++mi)
#pragma unroll
        for (int ni = 0; ni < 4; ++ni)
#pragma unroll
            for (int r = 0; r < 4; ++r) {
                int m = (int)m0 + wm * 64 + mi * 16 + quad * 4 + r;
                int n = (int)n0 + wn * 64 + ni * 16 + l16;
                epi(bz, m, n, acc[mi][ni][r]);
            }
}

// ---- epilogue functors -----------------------------------------------------
struct EpiRaw {            // kraw = key@Wk^T + bk   -> fp32 (16384 x 256)
    float* out; const float* bias;
    __device__ void operator()(int, int m, int n, float v) const {
        out[(long long)m * ZN + n] = v + bias[n];
    }
};
struct EpiQru {            // base = nq@Wqru^T + bqru; split q-raw / u / r
    float* qraw; u16* u; u16* r; const float* bqru;
    __device__ void operator()(int, int m, int n, float v) const {
        v += bqru[n];
        if (n < ZN) {
            qraw[(long long)m * ZN + n] = v;
        } else if (n < ZN + EN) {
            float s = 1.f / (1.f + __expf(-v));
            u[(long long)m * EN + (n - ZN)] = f2bf(s);
        } else {
            float s = v / (1.f + __expf(-v));
            r[(long long)m * EN + (n - ZN - EN)] = f2bf(s);
        }
    }
};
struct EpiV {              // v = silu(value@Wv^T + bv), stored (b, c, e) bf16
    u16* v; const float* bv;
    __device__ void operator()(int, int m, int n, float acc) const {
        float x = acc + bv[n];
        float s = x / (1.f + __expf(-x));
        int b = m & 7, c = m >> 3;
        v[((long long)b * LN_ + c) * EN + n] = f2bf(s);
    }
};
struct EpiQK {             // attn = relu(qk*scale + bias)^2, bf16 (b, s, c)
    u16* attn; const float* relpos;
    __device__ void operator()(int bz, int m, int n, float v) const {
        float val = v * LEN_SCALE + relpos[2047 + n - m];
        float t = fmaxf(val, 0.f);
        attn[(long long)bz * LN_ * LN_ + (long long)m * LN_ + n] = f2bf(t * t);
    }
};
struct EpiH {              // hr = (attn@v) * r, bf16 rows (s*8+b)
    u16* hr; const u16* r;
    __device__ void operator()(int bz, int m, int n, float acc) const {
        long long idx = ((long long)m * BN_ + bz) * EN + n;
        hr[idx] = f2bf(acc * bf2f(r[idx]));
    }
};
struct EpiOut {            // out = query + u*((hr@Wh^T + bh) - query), fp32
    float* out; const float* query; const u16* u; const float* bh;
    __device__ void operator()(int, int m, int n, float acc) const {
        long long idx = (long long)m * EN + n;
        float qv = query[idx];
        float uu = bf2f(u[idx]);
        out[idx] = qv + uu * ((acc + bh[n]) - qv);
    }
};

// ---------------------------------------------------------------------------
// prep: LN(query)->nq bf16; cast key_in, value -> bf16.  1 block per row.
// ---------------------------------------------------------------------------
__global__ __launch_bounds__(256)
void prep_kernel(const float* __restrict__ query, const float* __restrict__ key_in,
                 const float* __restrict__ value, const float* __restrict__ ln_w,
                 const float* __restrict__ ln_b,
                 u16* __restrict__ nq, u16* __restrict__ kin, u16* __restrict__ val)
{
    __shared__ float r1[4], r2[4];
    const int m = blockIdx.x, t = threadIdx.x;
    const long long base = (long long)m * EN + t * 4;
    float4 q = *(const float4*)(query + base);
    float a1 = q.x + q.y + q.z + q.w;
    float a2 = q.x * q.x + q.y * q.y + q.z * q.z + q.w * q.w;
#pragma unroll
    for (int o = 32; o; o >>= 1) { a1 += __shfl_down(a1, o, 64); a2 += __shfl_down(a2, o, 64); }
    if ((t & 63) == 0) { r1[t >> 6] = a1; r2[t >> 6] = a2; }
    __syncthreads();
    const float S1 = r1[0] + r1[1] + r1[2] + r1[3];
    const float S2 = r2[0] + r2[1] + r2[2] + r2[3];
    const float mu = S1 * (1.f / EN);
    const float var = S2 * (1.f / EN) - mu * mu;
    const float rstd = rsqrtf(var + 1e-5f);
    const int e = t * 4;
    float4 wv = *(const float4*)(ln_w + e);
    float4 bv = *(const float4*)(ln_b + e);
    store_bf16x4(nq + base, (q.x - mu) * rstd * wv.x + bv.x, (q.y - mu) * rstd * wv.y + bv.y,
                            (q.z - mu) * rstd * wv.z + bv.z, (q.w - mu) * rstd * wv.w + bv.w);
    float4 kq = *(const float4*)(key_in + base);
    store_bf16x4(kin + base, kq.x, kq.y, kq.z, kq.w);
    float4 vq = *(const float4*)(value + base);
    store_bf16x4(val + base, vq.x, vq.y, vq.z, vq.w);
}

// ---------------------------------------------------------------------------
// l2norm over Z=256 + scale/shift; raw (16384 x 256) fp32 -> out (b, s, z) bf16
// ---------------------------------------------------------------------------
__global__ __launch_bounds__(256)
void l2norm_scale(const float* __restrict__ raw, u16* __restrict__ out,
                  const float* __restrict__ gamma, const float* __restrict__ beta)
{
    __shared__ float red[4];
    const int m = blockIdx.x, z = threadIdx.x;
    const float x = raw[(long long)m * ZN + z];
    float ss = x * x;
#pragma unroll
    for (int o = 32; o; o >>= 1) ss += __shfl_down(ss, o, 64);
    if ((z & 63) == 0) red[z >> 6] = ss;
    __syncthreads();
    const float tot = red[0] + red[1] + red[2] + red[3];
    const float inv = 1.f / fmaxf(sqrtf(tot), 1e-5f);
    const float res = x * inv * (gamma[z] + 1.f) + beta[z];
    const int b = m & 7, s = m >> 3;
    out[((long long)b * LN_ + s) * ZN + z] = f2bf(res);
}

// ---------------------------------------------------------------------------
// transpose v (b, c, e) -> vT (b, e, c), bf16, 64x64 LDS tiles
// ---------------------------------------------------------------------------
__global__ __launch_bounds__(256)
void transpose_bc(const u16* __restrict__ v, u16* __restrict__ vT)
{
    __shared__ u16 tile[64][65];
    const int b = blockIdx.z;
    const int c0 = blockIdx.y * 64, e0 = blockIdx.x * 64;
    const int tx = threadIdx.x & 63, ty = threadIdx.x >> 6;
    const u16* src = v + (long long)b * LN_ * EN;
    u16* dst = vT + (long long)b * EN * LN_;
#pragma unroll
    for (int i = 0; i < 64; i += 4)
        tile[ty + i][tx] = src[(long long)(c0 + ty + i) * EN + (e0 + tx)];
    __syncthreads();
#pragma unroll
    for (int i = 0; i < 64; i += 4)
        dst[(long long)(e0 + ty + i) * LN_ + (c0 + tx)] = tile[tx][ty + i];
}

// ---------------------------------------------------------------------------
__global__ __launch_bounds__(256)
void castw(const float* __restrict__ in, u16* __restrict__ out, int n4)
{
    const int i = blockIdx.x * 256 + threadIdx.x;
    if (i < n4) {
        float4 x = ((const float4*)in)[i];
        store_bf16x4(out + (long long)i * 4, x.x, x.y, x.z, x.w);
    }
}

// ---------------------------------------------------------------------------
extern "C" void kernel_launch(void* const* d_in, const int* in_sizes, int n_in,
                              void* d_out, int out_size, void* d_ws, size_t ws_size,
                              hipStream_t stream)
{
    const float* query  = (const float*)d_in[0];
    const float* key_in = (const float*)d_in[1];
    const float* value  = (const float*)d_in[2];
    const float* ln_w   = (const float*)d_in[3];
    const float* ln_b   = (const float*)d_in[4];
    const float* Wv     = (const float*)d_in[5];
    const float* bv     = (const float*)d_in[6];
    const float* Wk     = (const float*)d_in[7];
    const float* bk     = (const float*)d_in[8];
    const float* Wqru   = (const float*)d_in[9];
    const float* bqru   = (const float*)d_in[10];
    const float* Wh     = (const float*)d_in[11];
    const float* bh     = (const float*)d_in[12];
    const float* gamma  = (const float*)d_in[13];
    const float* beta   = (const float*)d_in[14];
    const float* relpos = (const float*)d_in[15];
    float* out = (float*)d_out;

    char* ws = (char*)d_ws;
    const size_t MB = 1ull << 20;
    u16*   nq    = (u16*)(ws + 0);          // 32 MiB, dead after GEMM-qru
    u16*   kin   = (u16*)(ws + 32 * MB);    // 32 MiB, dead after GEMM-k
    u16*   vbce  = (u16*)(ws + 32 * MB);    // 32 MiB (aliases kin)
    u16*   attn  = (u16*)(ws + 0);          // 64 MiB (aliases nq+kin/vbce)
    u16*   valb  = (u16*)(ws + 64 * MB);    // 32 MiB, dead after GEMM-v
    u16*   hr    = (u16*)(ws + 64 * MB);    // 32 MiB (aliases valb)
    u16*   qb    = (u16*)(ws + 96 * MB);    // 8 MiB  (b,s,z)
    u16*   kb    = (u16*)(ws + 104 * MB);   // 8 MiB  (b,c,z)
    u16*   ub    = (u16*)(ws + 112 * MB);   // 32 MiB
    u16*   rb    = (u16*)(ws + 144 * MB);   // 32 MiB
    u16*   vT    = (u16*)(ws + 176 * MB);   // 32 MiB (b,e,c)
    float* raw   = (float*)(ws + 208 * MB); // 16 MiB (kraw then qraw)
    u16*   WqruB = (u16*)(ws + 224 * MB);   // 4.5 MiB
    u16*   WkB   = (u16*)(ws + 229 * MB);   // 0.5 MiB
    u16*   WvB   = (u16*)(ws + 230 * MB);   // 2 MiB
    u16*   WhB   = (u16*)(ws + 232 * MB);   // 2 MiB   (total 234 MiB)
    (void)ws_size; (void)in_sizes; (void)n_in; (void)out_size;

    // 1) cast weights to bf16
    castw<<<dim3(QRU_N * EN / 4 / 256), 256, 0, stream>>>(Wqru, WqruB, QRU_N * EN / 4);
    castw<<<dim3(ZN * EN / 4 / 256), 256, 0, stream>>>(Wk, WkB, ZN * EN / 4);
    castw<<<dim3(EN * EN / 4 / 256), 256, 0, stream>>>(Wv, WvB, EN * EN / 4);
    castw<<<dim3(EN * EN / 4 / 256), 256, 0, stream>>>(Wh, WhB, EN * EN / 4);

    // 2) layernorm(query) + bf16 casts of key/value
    prep_kernel<<<dim3(MROWS), 256, 0, stream>>>(query, key_in, value, ln_w, ln_b, nq, kin, valb);

    // 3) k = l2norm(key@Wk^T + bk)*g1 + beta1   (128^2 engine: N=256)
    gemm_bt<<<dim3(ZN / 128, MROWS / 128, 1), 256, 0, stream>>>(
        kin, WkB, 0LL, 0LL, EN, EpiRaw{raw, bk});
    l2norm_scale<<<dim3(MROWS), 256, 0, stream>>>(raw, kb, gamma + ZN, beta + ZN);

    // 4) base = nq@Wqru^T + bqru -> qraw / u / r   (9 x 64 blocks)
    gemm256<<<dim3(QRU_N / 256, MROWS / 256, 1), 512, 0, stream>>>(
        nq, WqruB, 0LL, 0LL, EN, EpiQru{raw, ub, rb, bqru});
    l2norm_scale<<<dim3(MROWS), 256, 0, stream>>>(raw, qb, gamma, beta);

    // 5) v = silu(value@Wv^T + bv)  (b,c,e), then transpose to (b,e,c)
    gemm256<<<dim3(EN / 256, MROWS / 256, 1), 512, 0, stream>>>(
        valb, WvB, 0LL, 0LL, EN, EpiV{vbce, bv});
    transpose_bc<<<dim3(EN / 64, LN_ / 64, BN_), 256, 0, stream>>>(vbce, vT);

    // 6) attn = relu(q@k^T * scale + bias)^2   (8 x 8 x 8 blocks)
    gemm256<<<dim3(LN_ / 256, LN_ / 256, BN_), 512, 0, stream>>>(
        qb, kb, (long long)LN_ * ZN, (long long)LN_ * ZN, ZN, EpiQK{attn, relpos});

    // 7) hr = (attn @ v) * r   (4 x 8 x 8 blocks)
    gemm256<<<dim3(EN / 256, LN_ / 256, BN_), 512, 0, stream>>>(
        attn, vT, (long long)LN_ * LN_, (long long)EN * LN_, LN_, EpiH{hr, rb});

    // 8) out = query + u*((hr@Wh^T + bh) - query)
    gemm256<<<dim3(EN / 256, MROWS / 256, 1), 512, 0, stream>>>(
        hr, WhB, 0LL, 0LL, EN, EpiOut{out, query, ub, bh});
}

// Round 3
// 705.835 us; speedup vs baseline: 1.1099x; 1.1087x over previous
//
#include <hip/hip_runtime.h>
#include <cstdint>

// ---------------------------------------------------------------------------
// GatedCrossAttention  (E=1024, Z=256, L=2048, B=8)
// bf16 MFMA GEMMs (16x16x32), BK=64 K-loop, XOR-swizzled LDS, fused epilogues.
// Round 3: proven 128^2 engine everywhere + XCD-aware block swizzle (T1).
// ---------------------------------------------------------------------------

#define EN 1024
#define ZN 256
#define LN_ 2048
#define BN_ 8
#define MROWS (LN_ * BN_)          // 16384
#define QRU_N (2 * EN + ZN)        // 2304
#define LEN_SCALE 0.022097086912079608f  // 1/sqrt(2048)

typedef unsigned short u16;
typedef __bf16 bf16x8 __attribute__((ext_vector_type(8)));
typedef float f32x4 __attribute__((ext_vector_type(4)));

// ---- bf16 helpers ---------------------------------------------------------
__device__ __forceinline__ u16 f2bf(float f) {
    unsigned int u = __float_as_uint(f);
    u = (u + 0x7fff + ((u >> 16) & 1)) >> 16;
    return (u16)u;
}
__device__ __forceinline__ float bf2f(u16 s) {
    return __uint_as_float(((unsigned int)s) << 16);
}
__device__ __forceinline__ void store_bf16x4(u16* p, float a, float b, float c, float d) {
    union { u16 h[4]; uint2 v; } pk;
    pk.h[0] = f2bf(a); pk.h[1] = f2bf(b); pk.h[2] = f2bf(c); pk.h[3] = f2bf(d);
    *(uint2*)p = pk.v;
}

// ---- async global->LDS (16B/lane, wave-uniform LDS base + lane*16) --------
__device__ __forceinline__ void async_load16(const void* g, void* l) {
    __builtin_amdgcn_global_load_lds(
        (const __attribute__((address_space(1))) void*)g,
        (__attribute__((address_space(3))) void*)l,
        16, 0, 0);
}

// ---------------------------------------------------------------------------
// GEMM-BT: C[M,N] = A[M,K] @ B[N,K]^T, A/B bf16 row-major, epilogue functor.
// Block 256 (4 waves, 2x2 wave grid), tile 128x128, BK=64.
// LDS rows are 64 elems (128 B = all 32 banks); the 16B chunk index is
// XOR-swizzled by (row&7) so ds_read_b128 spreads 2 lanes/bank (free, m136).
// Swizzle is applied on the GLOBAL source address of global_load_lds (the
// LDS destination is hardware-fixed at base+lane*16) and undone on read.
// T1: XCD-aware block swizzle (bijective; all grids here have nwg % 8 == 0).
// Requires M%128==0, N%128==0, K%64==0.
// ---------------------------------------------------------------------------
template <typename Epi>
__global__ __launch_bounds__(256, 4)
void gemm_bt(const u16* __restrict__ A, const u16* __restrict__ B,
             long long batchStrideA, long long batchStrideB, int K, Epi epi)
{
    __shared__ __align__(16) u16 As[128 * 64];
    __shared__ __align__(16) u16 Bs[128 * 64];

    const int tid  = threadIdx.x;
    const int lane = tid & 63;
    const int w    = tid >> 6;
    const int wm   = w >> 1, wn = w & 1;
    const int bz   = blockIdx.z;

    // T1: XCD-aware swizzle of the (x,y) block index
    const int gx   = gridDim.x;
    const int nwg  = gx * gridDim.y;
    const int orig = blockIdx.y * gx + blockIdx.x;
    const int swz  = ((nwg & 7) == 0) ? ((orig & 7) * (nwg >> 3) + (orig >> 3)) : orig;
    const long long m0 = (long long)(swz / gx) * 128;
    const long long n0 = (long long)(swz % gx) * 128;

    const u16* Ab = A + bz * batchStrideA;
    const u16* Bb = B + bz * batchStrideB;

    // staging: lane covers row (lane>>3) of each 8-row group, swizzled chunk
    const int srow = lane >> 3;                          // 0..7
    const int scol = ((lane & 7) ^ srow) * 8;            // swizzled source col
    const int quad = lane >> 4;
    const int l16  = lane & 15;

    // read-side swizzled chunk offsets (elems), constant per lane
    const int choff0 = ((quad     ^ (l16 & 7)) * 8);     // k-half 0
    const int choff1 = (((4 + quad) ^ (l16 & 7)) * 8);   // k-half 1

    const f32x4 fzero = {0.f, 0.f, 0.f, 0.f};
    f32x4 acc[4][4];
#pragma unroll
    for (int i = 0; i < 4; ++i)
#pragma unroll
        for (int j = 0; j < 4; ++j) acc[i][j] = fzero;

    for (int k0 = 0; k0 < K; k0 += 64) {
        __syncthreads();   // prior-iter LDS reads done before overwrite
#pragma unroll
        for (int t = 0; t < 4; ++t) {
            const int rbase = w * 32 + t * 8;
            async_load16(Ab + (m0 + rbase + srow) * K + (k0 + scol), (void*)&As[rbase * 64]);
            async_load16(Bb + (n0 + rbase + srow) * K + (k0 + scol), (void*)&Bs[rbase * 64]);
        }
        __builtin_amdgcn_s_waitcnt(0);
        __syncthreads();

#pragma unroll
        for (int h = 0; h < 2; ++h) {
            const int ch = h ? choff1 : choff0;
            bf16x8 af[4], bfv[4];
#pragma unroll
            for (int mi = 0; mi < 4; ++mi)
                af[mi] = *(const bf16x8*)&As[(wm * 64 + mi * 16 + l16) * 64 + ch];
#pragma unroll
            for (int ni = 0; ni < 4; ++ni)
                bfv[ni] = *(const bf16x8*)&Bs[(wn * 64 + ni * 16 + l16) * 64 + ch];
#pragma unroll
            for (int mi = 0; mi < 4; ++mi)
#pragma unroll
                for (int ni = 0; ni < 4; ++ni)
                    acc[mi][ni] = __builtin_amdgcn_mfma_f32_16x16x32_bf16(
                        af[mi], bfv[ni], acc[mi][ni], 0, 0, 0);
        }
    }

    // epilogue: D[row][col], col = lane&15, row = quad*4 + reg  [verified m89/m91]
#pragma unroll
    for (int mi = 0; mi < 4; ++mi)
#pragma unroll
        for (int ni = 0; ni < 4; ++ni)
#pragma unroll
            for (int r = 0; r < 4; ++r) {
                int m = (int)m0 + wm * 64 + mi * 16 + quad * 4 + r;
                int n = (int)n0 + wn * 64 + ni * 16 + l16;
                epi(bz, m, n, acc[mi][ni][r]);
            }
}

// ---- epilogue functors -----------------------------------------------------
struct EpiRaw {            // kraw = key@Wk^T + bk   -> fp32 (16384 x 256)
    float* out; const float* bias;
    __device__ void operator()(int, int m, int n, float v) const {
        out[(long long)m * ZN + n] = v + bias[n];
    }
};
struct EpiQru {            // base = nq@Wqru^T + bqru; split q-raw / u / r
    float* qraw; u16* u; u16* r; const float* bqru;
    __device__ void operator()(int, int m, int n, float v) const {
        v += bqru[n];
        if (n < ZN) {
            qraw[(long long)m * ZN + n] = v;
        } else if (n < ZN + EN) {
            float s = 1.f / (1.f + __expf(-v));
            u[(long long)m * EN + (n - ZN)] = f2bf(s);
        } else {
            float s = v / (1.f + __expf(-v));
            r[(long long)m * EN + (n - ZN - EN)] = f2bf(s);
        }
    }
};
struct EpiV {              // v = silu(value@Wv^T + bv), stored (b, c, e) bf16
    u16* v; const float* bv;
    __device__ void operator()(int, int m, int n, float acc) const {
        float x = acc + bv[n];
        float s = x / (1.f + __expf(-x));
        int b = m & 7, c = m >> 3;
        v[((long long)b * LN_ + c) * EN + n] = f2bf(s);
    }
};
struct EpiQK {             // attn = relu(qk*scale + bias)^2, bf16 (b, s, c)
    u16* attn; const float* relpos;
    __device__ void operator()(int bz, int m, int n, float v) const {
        float val = v * LEN_SCALE + relpos[2047 + n - m];
        float t = fmaxf(val, 0.f);
        attn[(long long)bz * LN_ * LN_ + (long long)m * LN_ + n] = f2bf(t * t);
    }
};
struct EpiH {              // hr = (attn@v) * r, bf16 rows (s*8+b)
    u16* hr; const u16* r;
    __device__ void operator()(int bz, int m, int n, float acc) const {
        long long idx = ((long long)m * BN_ + bz) * EN + n;
        hr[idx] = f2bf(acc * bf2f(r[idx]));
    }
};
struct EpiOut {            // out = query + u*((hr@Wh^T + bh) - query), fp32
    float* out; const float* query; const u16* u; const float* bh;
    __device__ void operator()(int, int m, int n, float acc) const {
        long long idx = (long long)m * EN + n;
        float qv = query[idx];
        float uu = bf2f(u[idx]);
        out[idx] = qv + uu * ((acc + bh[n]) - qv);
    }
};

// ---------------------------------------------------------------------------
// prep: LN(query)->nq bf16; cast key_in, value -> bf16.  1 block per row.
// ---------------------------------------------------------------------------
__global__ __launch_bounds__(256)
void prep_kernel(const float* __restrict__ query, const float* __restrict__ key_in,
                 const float* __restrict__ value, const float* __restrict__ ln_w,
                 const float* __restrict__ ln_b,
                 u16* __restrict__ nq, u16* __restrict__ kin, u16* __restrict__ val)
{
    __shared__ float r1[4], r2[4];
    const int m = blockIdx.x, t = threadIdx.x;
    const long long base = (long long)m * EN + t * 4;
    float4 q = *(const float4*)(query + base);
    float a1 = q.x + q.y + q.z + q.w;
    float a2 = q.x * q.x + q.y * q.y + q.z * q.z + q.w * q.w;
#pragma unroll
    for (int o = 32; o; o >>= 1) { a1 += __shfl_down(a1, o, 64); a2 += __shfl_down(a2, o, 64); }
    if ((t & 63) == 0) { r1[t >> 6] = a1; r2[t >> 6] = a2; }
    __syncthreads();
    const float S1 = r1[0] + r1[1] + r1[2] + r1[3];
    const float S2 = r2[0] + r2[1] + r2[2] + r2[3];
    const float mu = S1 * (1.f / EN);
    const float var = S2 * (1.f / EN) - mu * mu;
    const float rstd = rsqrtf(var + 1e-5f);
    const int e = t * 4;
    float4 wv = *(const float4*)(ln_w + e);
    float4 bv = *(const float4*)(ln_b + e);
    store_bf16x4(nq + base, (q.x - mu) * rstd * wv.x + bv.x, (q.y - mu) * rstd * wv.y + bv.y,
                            (q.z - mu) * rstd * wv.z + bv.z, (q.w - mu) * rstd * wv.w + bv.w);
    float4 kq = *(const float4*)(key_in + base);
    store_bf16x4(kin + base, kq.x, kq.y, kq.z, kq.w);
    float4 vq = *(const float4*)(value + base);
    store_bf16x4(val + base, vq.x, vq.y, vq.z, vq.w);
}

// ---------------------------------------------------------------------------
// l2norm over Z=256 + scale/shift; raw (16384 x 256) fp32 -> out (b, s, z) bf16
// ---------------------------------------------------------------------------
__global__ __launch_bounds__(256)
void l2norm_scale(const float* __restrict__ raw, u16* __restrict__ out,
                  const float* __restrict__ gamma, const float* __restrict__ beta)
{
    __shared__ float red[4];
    const int m = blockIdx.x, z = threadIdx.x;
    const float x = raw[(long long)m * ZN + z];
    float ss = x * x;
#pragma unroll
    for (int o = 32; o; o >>= 1) ss += __shfl_down(ss, o, 64);
    if ((z & 63) == 0) red[z >> 6] = ss;
    __syncthreads();
    const float tot = red[0] + red[1] + red[2] + red[3];
    const float inv = 1.f / fmaxf(sqrtf(tot), 1e-5f);
    const float res = x * inv * (gamma[z] + 1.f) + beta[z];
    const int b = m & 7, s = m >> 3;
    out[((long long)b * LN_ + s) * ZN + z] = f2bf(res);
}

// ---------------------------------------------------------------------------
// transpose v (b, c, e) -> vT (b, e, c), bf16, 64x64 LDS tiles
// ---------------------------------------------------------------------------
__global__ __launch_bounds__(256)
void transpose_bc(const u16* __restrict__ v, u16* __restrict__ vT)
{
    __shared__ u16 tile[64][65];
    const int b = blockIdx.z;
    const int c0 = blockIdx.y * 64, e0 = blockIdx.x * 64;
    const int tx = threadIdx.x & 63, ty = threadIdx.x >> 6;
    const u16* src = v + (long long)b * LN_ * EN;
    u16* dst = vT + (long long)b * EN * LN_;
#pragma unroll
    for (int i = 0; i < 64; i += 4)
        tile[ty + i][tx] = src[(long long)(c0 + ty + i) * EN + (e0 + tx)];
    __syncthreads();
#pragma unroll
    for (int i = 0; i < 64; i += 4)
        dst[(long long)(e0 + ty + i) * LN_ + (c0 + tx)] = tile[tx][ty + i];
}

// ---------------------------------------------------------------------------
__global__ __launch_bounds__(256)
void castw(const float* __restrict__ in, u16* __restrict__ out, int n4)
{
    const int i = blockIdx.x * 256 + threadIdx.x;
    if (i < n4) {
        float4 x = ((const float4*)in)[i];
        store_bf16x4(out + (long long)i * 4, x.x, x.y, x.z, x.w);
    }
}

// ---------------------------------------------------------------------------
extern "C" void kernel_launch(void* const* d_in, const int* in_sizes, int n_in,
                              void* d_out, int out_size, void* d_ws, size_t ws_size,
                              hipStream_t stream)
{
    const float* query  = (const float*)d_in[0];
    const float* key_in = (const float*)d_in[1];
    const float* value  = (const float*)d_in[2];
    const float* ln_w   = (const float*)d_in[3];
    const float* ln_b   = (const float*)d_in[4];
    const float* Wv     = (const float*)d_in[5];
    const float* bv     = (const float*)d_in[6];
    const float* Wk     = (const float*)d_in[7];
    const float* bk     = (const float*)d_in[8];
    const float* Wqru   = (const float*)d_in[9];
    const float* bqru   = (const float*)d_in[10];
    const float* Wh     = (const float*)d_in[11];
    const float* bh     = (const float*)d_in[12];
    const float* gamma  = (const float*)d_in[13];
    const float* beta   = (const float*)d_in[14];
    const float* relpos = (const float*)d_in[15];
    float* out = (float*)d_out;

    char* ws = (char*)d_ws;
    const size_t MB = 1ull << 20;
    // region1 (0..64MB): nq | kin/vbce  -> later attn (full 64MB)
    u16*   nq    = (u16*)(ws + 0);          // 32 MiB, dead after GEMM-qru
    u16*   kin   = (u16*)(ws + 32 * MB);    // 32 MiB, dead after GEMM-k
    u16*   vbce  = (u16*)(ws + 32 * MB);    // 32 MiB (aliases kin), dead after transpose
    u16*   attn  = (u16*)(ws + 0);          // 64 MiB (aliases nq+kin/vbce)
    // region2 (64..96MB): val -> later hr
    u16*   valb  = (u16*)(ws + 64 * MB);    // 32 MiB, dead after GEMM-v
    u16*   hr    = (u16*)(ws + 64 * MB);    // 32 MiB (aliases valb)
    // persistent region (96MB..):
    u16*   qb    = (u16*)(ws + 96 * MB);    // 8 MiB  (b,s,z)
    u16*   kb    = (u16*)(ws + 104 * MB);   // 8 MiB  (b,c,z)
    u16*   ub    = (u16*)(ws + 112 * MB);   // 32 MiB
    u16*   rb    = (u16*)(ws + 144 * MB);   // 32 MiB
    u16*   vT    = (u16*)(ws + 176 * MB);   // 32 MiB (b,e,c)
    float* raw   = (float*)(ws + 208 * MB); // 16 MiB (shared by kraw then qraw)
    u16*   WqruB = (u16*)(ws + 224 * MB);   // 4.5 MiB
    u16*   WkB   = (u16*)(ws + 229 * MB);   // 0.5 MiB
    u16*   WvB   = (u16*)(ws + 230 * MB);   // 2 MiB
    u16*   WhB   = (u16*)(ws + 232 * MB);   // 2 MiB   (total 234 MiB)
    (void)ws_size; (void)in_sizes; (void)n_in; (void)out_size;

    // 1) cast weights to bf16
    castw<<<dim3(QRU_N * EN / 4 / 256), 256, 0, stream>>>(Wqru, WqruB, QRU_N * EN / 4);
    castw<<<dim3(ZN * EN / 4 / 256), 256, 0, stream>>>(Wk, WkB, ZN * EN / 4);
    castw<<<dim3(EN * EN / 4 / 256), 256, 0, stream>>>(Wv, WvB, EN * EN / 4);
    castw<<<dim3(EN * EN / 4 / 256), 256, 0, stream>>>(Wh, WhB, EN * EN / 4);

    // 2) layernorm(query) + bf16 casts of key/value
    prep_kernel<<<dim3(MROWS), 256, 0, stream>>>(query, key_in, value, ln_w, ln_b, nq, kin, valb);

    // 3) k = l2norm(key@Wk^T + bk)*g1 + beta1
    gemm_bt<<<dim3(ZN / 128, MROWS / 128, 1), 256, 0, stream>>>(
        kin, WkB, 0LL, 0LL, EN, EpiRaw{raw, bk});
    l2norm_scale<<<dim3(MROWS), 256, 0, stream>>>(raw, kb, gamma + ZN, beta + ZN);

    // 4) base = nq@Wqru^T + bqru -> qraw / u / r
    gemm_bt<<<dim3(QRU_N / 128, MROWS / 128, 1), 256, 0, stream>>>(
        nq, WqruB, 0LL, 0LL, EN, EpiQru{raw, ub, rb, bqru});
    l2norm_scale<<<dim3(MROWS), 256, 0, stream>>>(raw, qb, gamma, beta);

    // 5) v = silu(value@Wv^T + bv)  (b,c,e), then transpose to (b,e,c)
    gemm_bt<<<dim3(EN / 128, MROWS / 128, 1), 256, 0, stream>>>(
        valb, WvB, 0LL, 0LL, EN, EpiV{vbce, bv});
    transpose_bc<<<dim3(EN / 64, LN_ / 64, BN_), 256, 0, stream>>>(vbce, vT);

    // 6) attn = relu(q@k^T * scale + bias)^2   (batched over b)
    gemm_bt<<<dim3(LN_ / 128, LN_ / 128, BN_), 256, 0, stream>>>(
        qb, kb, (long long)LN_ * ZN, (long long)LN_ * ZN, ZN, EpiQK{attn, relpos});

    // 7) hr = (attn @ v) * r   (batched over b)
    gemm_bt<<<dim3(EN / 128, LN_ / 128, BN_), 256, 0, stream>>>(
        attn, vT, (long long)LN_ * LN_, (long long)EN * LN_, LN_, EpiH{hr, rb});

    // 8) out = query + u*((hr@Wh^T + bh) - query)
    gemm_bt<<<dim3(EN / 128, MROWS / 128, 1), 256, 0, stream>>>(
        hr, WhB, 0LL, 0LL, EN, EpiOut{out, query, ub, bh});
}